// Round 6
// baseline (464.548 us; speedup 1.0000x reference)
//
#include <hip/hip_runtime.h>
#include <hip/hip_bf16.h>

#define IN_DIM 256
#define HID 128
#define CCH 2
#define RR 5
#define LL 2
#define NCLS 16

typedef __attribute__((ext_vector_type(8))) short short8;
typedef __attribute__((ext_vector_type(4))) short short4_;
typedef __attribute__((ext_vector_type(4))) float floatx4;

__device__ __forceinline__ unsigned short f2bf(float f) {
    unsigned int u = __float_as_uint(f);
    unsigned int r = (u + 0x7FFFu + ((u >> 16) & 1u)) >> 16;   // RN-even
    return (unsigned short)r;
}

// ---------------- fused: Filt softmax + weight convert/transpose ----------------
__global__ void cvt_weights(const float* __restrict__ Wc, const float* __restrict__ W1,
                            const float* __restrict__ gt_w,
                            unsigned short* __restrict__ WcT, unsigned short* __restrict__ W1T,
                            float* __restrict__ filt) {
    int i = blockIdx.x * 256 + threadIdx.x;
    if (blockIdx.x == 0 && threadIdx.x < LL * CCH) {
        const float* g = gt_w + threadIdx.x * RR;
        float m = -1e30f;
        for (int r = 0; r < RR; ++r) m = fmaxf(m, g[r]);
        float e[RR], s = 0.f;
        for (int r = 0; r < RR; ++r) { e[r] = __expf(g[r] - m); s += e[r]; }
        for (int r = 0; r < RR; ++r) filt[threadIdx.x * RR + r] = e[r] / s;
    }
    if (i < CCH * HID * IN_DIM) {            // 65536: WcT[c][d][k]
        int c = i >> 15;
        int rem = i & 32767;
        int d = rem >> 8;
        int k = rem & 255;
        WcT[i] = f2bf(Wc[((size_t)c * IN_DIM + k) * HID + d]);
    }
    if (i < HID * IN_DIM) {                  // 32768: W1T[d][k]
        int d = i >> 8;
        int k = i & 255;
        W1T[i] = f2bf(W1[(size_t)k * HID + d]);
    }
}

// ---------------- Projection via MFMA -> interleaved H0[n][m], m=c*128+d ----------------
__global__ __launch_bounds__(256) void proj_mfma(const float* __restrict__ h,
                                                 const unsigned short* __restrict__ WcT,
                                                 unsigned short* __restrict__ H0, int N) {
    int t = threadIdx.x;
    int wv = t >> 6, l = t & 63;
    int l15 = l & 15, lq = l >> 4;
    int node = blockIdx.x * 64 + wv * 16 + l15;
    int nclamp = node < N ? node : N - 1;

    short8 bfrag[8];
    const float* hrow = h + (size_t)nclamp * IN_DIM;
#pragma unroll
    for (int kk = 0; kk < 8; ++kk) {
        int k0 = kk * 32 + lq * 8;
        floatx4 f0 = *(const floatx4*)(hrow + k0);
        floatx4 f1 = *(const floatx4*)(hrow + k0 + 4);
        short8 b;
        b[0] = (short)f2bf(f0[0]); b[1] = (short)f2bf(f0[1]);
        b[2] = (short)f2bf(f0[2]); b[3] = (short)f2bf(f0[3]);
        b[4] = (short)f2bf(f1[0]); b[5] = (short)f2bf(f1[1]);
        b[6] = (short)f2bf(f1[2]); b[7] = (short)f2bf(f1[3]);
        bfrag[kk] = b;
    }

#pragma unroll
    for (int mt = 0; mt < 16; ++mt) {
        floatx4 acc = {0.f, 0.f, 0.f, 0.f};
        const unsigned short* arow = WcT + (size_t)(mt * 16 + l15) * IN_DIM;
#pragma unroll
        for (int kk = 0; kk < 8; ++kk) {
            short8 a = *(const short8*)(arow + kk * 32 + lq * 8);
            acc = __builtin_amdgcn_mfma_f32_16x16x32_bf16(a, bfrag[kk], acc, 0, 0, 0);
        }
        if (node < N) {
            int m0 = mt * 16 + lq * 4;          // 0..255 over (c,d), interleaved
            short4_ st;
            st[0] = (short)f2bf(acc[0]); st[1] = (short)f2bf(acc[1]);
            st[2] = (short)f2bf(acc[2]); st[3] = (short)f2bf(acc[3]);
            *(short4_*)(H0 + (size_t)node * (CCH * HID) + m0) = st;
        }
    }
}

// ---------------- CSR build ----------------
__global__ void count_kernel(const int* __restrict__ dst, int* __restrict__ counts, int E) {
    for (int e = blockIdx.x * blockDim.x + threadIdx.x; e < E; e += gridDim.x * blockDim.x)
        atomicAdd(&counts[dst[e]], 1);
}

__global__ void scanA_kernel(const int* __restrict__ counts, int* __restrict__ partials, int n) {
    __shared__ int s[256];
    int t = threadIdx.x;
    int i = blockIdx.x * 256 + t;
    int v = (i < n) ? counts[i] : 0;
    s[t] = v;
    __syncthreads();
    for (int off = 1; off < 256; off <<= 1) {
        int tv = (t >= off) ? s[t - off] : 0;
        __syncthreads();
        s[t] += tv;
        __syncthreads();
    }
    if (t == 255) partials[blockIdx.x] = s[255];
}

__global__ void scanB_kernel(const int* __restrict__ partials, int* __restrict__ chunk_off, int nchunk) {
    __shared__ int s[256];
    int t = threadIdx.x;
    int v = (t < nchunk) ? partials[t] : 0;
    s[t] = v;
    __syncthreads();
    for (int off = 1; off < 256; off <<= 1) {
        int tv = (t >= off) ? s[t - off] : 0;
        __syncthreads();
        s[t] += tv;
        __syncthreads();
    }
    if (t < nchunk) chunk_off[t] = s[t] - v;   // exclusive
}

__global__ void scanC_kernel(const int* __restrict__ counts, const int* __restrict__ chunk_off,
                             int* __restrict__ offsets, int* __restrict__ cursor, int n) {
    __shared__ int s[256];
    int t = threadIdx.x;
    int i = blockIdx.x * 256 + t;
    int v = (i < n) ? counts[i] : 0;
    s[t] = v;
    __syncthreads();
    for (int off = 1; off < 256; off <<= 1) {
        int tv = (t >= off) ? s[t - off] : 0;
        __syncthreads();
        s[t] += tv;
        __syncthreads();
    }
    if (i < n) {
        int incl = chunk_off[blockIdx.x] + s[t];
        offsets[i + 1] = incl;
        cursor[i] = incl - v;
    }
    if (i == 0) offsets[0] = 0;
}

__global__ void fill_kernel(const int* __restrict__ src, const int* __restrict__ dst,
                            const int* __restrict__ etype, int* __restrict__ cursor,
                            int2* __restrict__ epack, int E) {
    for (int e = blockIdx.x * blockDim.x + threadIdx.x; e < E; e += gridDim.x * blockDim.x) {
        int d = dst[e];
        int p = atomicAdd(&cursor[d], 1);
        epack[p] = make_int2(src[e], etype[e]);
    }
}

// ---------------- Aggregation (bf16 interleaved): 1 node/block, 2-way edge-parallel ----------------
__global__ __launch_bounds__(256) void agg_kernel(const unsigned int* __restrict__ Hin,
                                                  unsigned int* __restrict__ Hout,
                                                  const int* __restrict__ offs,
                                                  const int2* __restrict__ epack,
                                                  const float* __restrict__ filt, int N) {
    int node = blockIdx.x;
    int t = threadIdx.x;
    int ep = t >> 7;          // 0/1: edge-parallel group
    int q = t & 127;          // lane within row (128 uints = 256 bf16)
    int c = q >> 6;           // channel for filter weight
    float f0 = filt[c * RR + 0], f1 = filt[c * RR + 1], f2 = filt[c * RR + 2];
    float f3 = filt[c * RR + 3], f4 = filt[c * RR + 4];

    int e0 = offs[node], e1 = offs[node + 1];
    float ax = 0.f, ay = 0.f, deg = 0.f;

    int j = e0 + ep;
    if (j < e1) {
        int2 pc = epack[j];
        unsigned int v = Hin[(size_t)pc.x * 128 + q];   // in flight
        int et = pc.y;
        for (;;) {
            int jn = j + 2;
            unsigned int vc = v;
            int etc = et;
            if (jn < e1) {                              // prefetch next edge
                int2 pn = epack[jn];
                v = Hin[(size_t)pn.x * 128 + q];
                et = pn.y;
            }
            float w = (etc == 0) ? f0 : (etc == 1) ? f1 : (etc == 2) ? f2 : (etc == 3) ? f3 : f4;
            ax += w * __uint_as_float(vc << 16);
            ay += w * __uint_as_float(vc & 0xFFFF0000u);
            deg += w;
            j = jn;
            if (j >= e1) break;
        }
    }

    __shared__ float sax[128], say[128], sdeg[128];
    if (ep == 1) { sax[q] = ax; say[q] = ay; sdeg[q] = deg; }
    __syncthreads();
    if (ep == 0) {
        ax += sax[q]; ay += say[q]; deg += sdeg[q];
        float inv = 1.f / deg;
        unsigned int lo = f2bf(ax * inv);
        unsigned int hi = f2bf(ay * inv);
        Hout[(size_t)node * 128 + q] = lo | (hi << 16);
    }
}

// ---------------- MLP1 via MFMA on gathered interleaved rows ----------------
__global__ __launch_bounds__(256) void mlp1_mfma(const unsigned short* __restrict__ H2,
                                                 const int* __restrict__ cat,
                                                 const unsigned short* __restrict__ W1T,
                                                 const float* __restrict__ b1,
                                                 float* __restrict__ hidden, int NCAT) {
    int t = threadIdx.x;
    int wv = t >> 6, l = t & 63;
    int l15 = l & 15, lq = l >> 4;
    int i = blockIdx.x * 64 + wv * 16 + l15;
    int iclamp = i < NCAT ? i : NCAT - 1;
    int node = cat[iclamp];

    short8 bfrag[8];
    const unsigned short* xrow = H2 + (size_t)node * (CCH * HID);
#pragma unroll
    for (int kk = 0; kk < 8; ++kk)
        bfrag[kk] = *(const short8*)(xrow + kk * 32 + lq * 8);

#pragma unroll
    for (int mt = 0; mt < 8; ++mt) {
        floatx4 acc = {0.f, 0.f, 0.f, 0.f};
        const unsigned short* arow = W1T + (size_t)(mt * 16 + l15) * (CCH * HID);
#pragma unroll
        for (int kk = 0; kk < 8; ++kk) {
            short8 a = *(const short8*)(arow + kk * 32 + lq * 8);
            acc = __builtin_amdgcn_mfma_f32_16x16x32_bf16(a, bfrag[kk], acc, 0, 0, 0);
        }
        if (i < NCAT) {
            int d0 = mt * 16 + lq * 4;
            floatx4 o;
#pragma unroll
            for (int r = 0; r < 4; ++r) o[r] = fmaxf(acc[r] + b1[d0 + r], 0.f);
            *(floatx4*)(hidden + (size_t)i * HID + d0) = o;
        }
    }
}

// ---------------- MLP2 ----------------
__global__ void mlp2_kernel(const float* __restrict__ hidden, const float* __restrict__ W2,
                            const float* __restrict__ b2, float* __restrict__ out, int NCAT) {
    int idx = blockIdx.x * 256 + threadIdx.x;
    int i = idx >> 4, cls = idx & 15;
    if (i >= NCAT) return;
    const float* hrow = hidden + (size_t)i * HID;
    float acc = b2[cls];
#pragma unroll 8
    for (int j = 0; j < HID; ++j) acc += hrow[j] * W2[j * NCLS + cls];
    out[idx] = acc;
}

extern "C" void kernel_launch(void* const* d_in, const int* in_sizes, int n_in,
                              void* d_out, int out_size, void* d_ws, size_t ws_size,
                              hipStream_t stream) {
    const float* h    = (const float*)d_in[0];
    const int* src    = (const int*)d_in[1];
    const int* dst    = (const int*)d_in[2];
    const int* etype  = (const int*)d_in[3];
    const int* cat    = (const int*)d_in[4];
    const float* gt_w = (const float*)d_in[5];
    const float* Wc   = (const float*)d_in[6];
    const float* W1   = (const float*)d_in[7];
    const float* b1   = (const float*)d_in[8];
    const float* W2   = (const float*)d_in[9];
    const float* b2   = (const float*)d_in[10];
    float* out = (float*)d_out;

    const int N = in_sizes[0] / IN_DIM;   // 50000
    const int E = in_sizes[1];            // 500000
    const int NCAT = in_sizes[4];         // 10000
    const int NCHUNK = (N + 255) / 256;

    char* p = (char*)d_ws;
    auto alloc = [&](size_t bytes) {
        char* q = p;
        p += (bytes + 255) & ~(size_t)255;
        return q;
    };
    unsigned short* HA   = (unsigned short*)alloc((size_t)N * CCH * HID * 2);
    unsigned short* HB   = (unsigned short*)alloc((size_t)N * CCH * HID * 2);
    unsigned short* WcT  = (unsigned short*)alloc((size_t)CCH * HID * IN_DIM * 2);
    unsigned short* W1T  = (unsigned short*)alloc((size_t)HID * CCH * HID * 2);
    float* hidden        = (float*)alloc((size_t)NCAT * HID * 4);
    int*   counts        = (int*)alloc((size_t)N * 4);
    int*   offsets       = (int*)alloc((size_t)(N + 1) * 4);
    int*   cursor        = (int*)alloc((size_t)N * 4);
    int*   partials      = (int*)alloc((size_t)NCHUNK * 4);
    int*   chunk_off     = (int*)alloc((size_t)NCHUNK * 4);
    int2*  epack         = (int2*)alloc((size_t)E * 8);
    float* filt          = (float*)alloc((size_t)LL * CCH * RR * 4);

    hipMemsetAsync(counts, 0, (size_t)N * 4, stream);

    cvt_weights<<<(CCH * HID * IN_DIM + 255) / 256, 256, 0, stream>>>(Wc, W1, gt_w, WcT, W1T, filt);
    proj_mfma<<<(N + 63) / 64, 256, 0, stream>>>(h, WcT, HA, N);

    count_kernel<<<512, 256, 0, stream>>>(dst, counts, E);
    scanA_kernel<<<NCHUNK, 256, 0, stream>>>(counts, partials, N);
    scanB_kernel<<<1, 256, 0, stream>>>(partials, chunk_off, NCHUNK);
    scanC_kernel<<<NCHUNK, 256, 0, stream>>>(counts, chunk_off, offsets, cursor, N);
    fill_kernel<<<512, 256, 0, stream>>>(src, dst, etype, cursor, epack, E);

    agg_kernel<<<N, 256, 0, stream>>>((const unsigned int*)HA, (unsigned int*)HB,
                                      offsets, epack, filt, N);
    agg_kernel<<<N, 256, 0, stream>>>((const unsigned int*)HB, (unsigned int*)HA,
                                      offsets, epack, filt + CCH * RR, N);

    mlp1_mfma<<<(NCAT + 63) / 64, 256, 0, stream>>>(HA, cat, W1T, b1, hidden, NCAT);
    mlp2_kernel<<<(NCAT * NCLS + 255) / 256, 256, 0, stream>>>(hidden, W2, b2, out, NCAT);
}

// Round 7
// 355.743 us; speedup vs baseline: 1.3059x; 1.3059x over previous
//
#include <hip/hip_runtime.h>
#include <hip/hip_bf16.h>

#define IN_DIM 256
#define HID 128
#define CCH 2
#define RR 5
#define LL 2
#define NCLS 16

typedef __attribute__((ext_vector_type(8))) short short8;
typedef __attribute__((ext_vector_type(4))) short short4_;
typedef __attribute__((ext_vector_type(4))) float floatx4;

__device__ __forceinline__ unsigned short f2bf(float f) {
    unsigned int u = __float_as_uint(f);
    unsigned int r = (u + 0x7FFFu + ((u >> 16) & 1u)) >> 16;   // RN-even
    return (unsigned short)r;
}

// ---------------- fused: Filt softmax + weight convert/transpose ----------------
__global__ void cvt_weights(const float* __restrict__ Wc, const float* __restrict__ W1,
                            const float* __restrict__ gt_w,
                            unsigned short* __restrict__ WcT, unsigned short* __restrict__ W1T,
                            float* __restrict__ filt) {
    int i = blockIdx.x * 256 + threadIdx.x;
    if (blockIdx.x == 0 && threadIdx.x < LL * CCH) {
        const float* g = gt_w + threadIdx.x * RR;
        float m = -1e30f;
        for (int r = 0; r < RR; ++r) m = fmaxf(m, g[r]);
        float e[RR], s = 0.f;
        for (int r = 0; r < RR; ++r) { e[r] = __expf(g[r] - m); s += e[r]; }
        for (int r = 0; r < RR; ++r) filt[threadIdx.x * RR + r] = e[r] / s;
    }
    if (i < CCH * HID * IN_DIM) {            // 65536: WcT[c][d][k]
        int c = i >> 15;
        int rem = i & 32767;
        int d = rem >> 8;
        int k = rem & 255;
        WcT[i] = f2bf(Wc[((size_t)c * IN_DIM + k) * HID + d]);
    }
    if (i < HID * IN_DIM) {                  // 32768: W1T[d][k]
        int d = i >> 8;
        int k = i & 255;
        W1T[i] = f2bf(W1[(size_t)k * HID + d]);
    }
}

// ---------------- Projection via MFMA -> interleaved H0[n][m], m=c*128+d ----------------
__global__ __launch_bounds__(256) void proj_mfma(const float* __restrict__ h,
                                                 const unsigned short* __restrict__ WcT,
                                                 unsigned short* __restrict__ H0, int N) {
    int t = threadIdx.x;
    int wv = t >> 6, l = t & 63;
    int l15 = l & 15, lq = l >> 4;
    int node = blockIdx.x * 64 + wv * 16 + l15;
    int nclamp = node < N ? node : N - 1;

    short8 bfrag[8];
    const float* hrow = h + (size_t)nclamp * IN_DIM;
#pragma unroll
    for (int kk = 0; kk < 8; ++kk) {
        int k0 = kk * 32 + lq * 8;
        floatx4 f0 = *(const floatx4*)(hrow + k0);
        floatx4 f1 = *(const floatx4*)(hrow + k0 + 4);
        short8 b;
        b[0] = (short)f2bf(f0[0]); b[1] = (short)f2bf(f0[1]);
        b[2] = (short)f2bf(f0[2]); b[3] = (short)f2bf(f0[3]);
        b[4] = (short)f2bf(f1[0]); b[5] = (short)f2bf(f1[1]);
        b[6] = (short)f2bf(f1[2]); b[7] = (short)f2bf(f1[3]);
        bfrag[kk] = b;
    }

#pragma unroll
    for (int mt = 0; mt < 16; ++mt) {
        floatx4 acc = {0.f, 0.f, 0.f, 0.f};
        const unsigned short* arow = WcT + (size_t)(mt * 16 + l15) * IN_DIM;
#pragma unroll
        for (int kk = 0; kk < 8; ++kk) {
            short8 a = *(const short8*)(arow + kk * 32 + lq * 8);
            acc = __builtin_amdgcn_mfma_f32_16x16x32_bf16(a, bfrag[kk], acc, 0, 0, 0);
        }
        if (node < N) {
            int m0 = mt * 16 + lq * 4;          // 0..255 over (c,d), interleaved
            short4_ st;
            st[0] = (short)f2bf(acc[0]); st[1] = (short)f2bf(acc[1]);
            st[2] = (short)f2bf(acc[2]); st[3] = (short)f2bf(acc[3]);
            *(short4_*)(H0 + (size_t)node * (CCH * HID) + m0) = st;
        }
    }
}

// ---------------- CSR build ----------------
__global__ void count_kernel(const int* __restrict__ dst, int* __restrict__ counts, int E) {
    for (int e = blockIdx.x * blockDim.x + threadIdx.x; e < E; e += gridDim.x * blockDim.x)
        atomicAdd(&counts[dst[e]], 1);
}

__global__ void scanA_kernel(const int* __restrict__ counts, int* __restrict__ partials, int n) {
    __shared__ int s[256];
    int t = threadIdx.x;
    int i = blockIdx.x * 256 + t;
    int v = (i < n) ? counts[i] : 0;
    s[t] = v;
    __syncthreads();
    for (int off = 1; off < 256; off <<= 1) {
        int tv = (t >= off) ? s[t - off] : 0;
        __syncthreads();
        s[t] += tv;
        __syncthreads();
    }
    if (t == 255) partials[blockIdx.x] = s[255];
}

__global__ void scanB_kernel(const int* __restrict__ partials, int* __restrict__ chunk_off, int nchunk) {
    __shared__ int s[256];
    int t = threadIdx.x;
    int v = (t < nchunk) ? partials[t] : 0;
    s[t] = v;
    __syncthreads();
    for (int off = 1; off < 256; off <<= 1) {
        int tv = (t >= off) ? s[t - off] : 0;
        __syncthreads();
        s[t] += tv;
        __syncthreads();
    }
    if (t < nchunk) chunk_off[t] = s[t] - v;   // exclusive
}

__global__ void scanC_kernel(const int* __restrict__ counts, const int* __restrict__ chunk_off,
                             int* __restrict__ offsets, int* __restrict__ cursor, int n) {
    __shared__ int s[256];
    int t = threadIdx.x;
    int i = blockIdx.x * 256 + t;
    int v = (i < n) ? counts[i] : 0;
    s[t] = v;
    __syncthreads();
    for (int off = 1; off < 256; off <<= 1) {
        int tv = (t >= off) ? s[t - off] : 0;
        __syncthreads();
        s[t] += tv;
        __syncthreads();
    }
    if (i < n) {
        int incl = chunk_off[blockIdx.x] + s[t];
        offsets[i + 1] = incl;
        cursor[i] = incl - v;
    }
    if (i == 0) offsets[0] = 0;
}

__global__ void fill_kernel(const int* __restrict__ src, const int* __restrict__ dst,
                            const int* __restrict__ etype, int* __restrict__ cursor,
                            int2* __restrict__ epack, int E) {
    for (int e = blockIdx.x * blockDim.x + threadIdx.x; e < E; e += gridDim.x * blockDim.x) {
        int d = dst[e];
        int p = atomicAdd(&cursor[d], 1);
        epack[p] = make_int2(src[e], etype[e]);
    }
}

// ---------------- Aggregation: 1 node/block, 8 edge-groups x 32 lanes x 16B ----------------
// Row = 256 bf16 = 512B = 32 x uint4. Group g handles edges e0+g, e0+g+8, ...
__global__ __launch_bounds__(256) void agg_kernel(const uint4* __restrict__ Hin,
                                                  uint4* __restrict__ Hout,
                                                  const int* __restrict__ offs,
                                                  const int2* __restrict__ epack,
                                                  const float* __restrict__ filt, int N) {
    int node = blockIdx.x;
    int t = threadIdx.x;
    int g = t >> 5;            // edge group 0..7
    int lane32 = t & 31;       // 16B chunk within the 512B row
    int c = lane32 >> 4;       // channel: chunks 0-15 -> c=0, 16-31 -> c=1
    float f0 = filt[c * RR + 0], f1 = filt[c * RR + 1], f2 = filt[c * RR + 2];
    float f3 = filt[c * RR + 3], f4 = filt[c * RR + 4];

    int e0 = offs[node], e1 = offs[node + 1];
    float acc[8];
#pragma unroll
    for (int r = 0; r < 8; ++r) acc[r] = 0.f;
    float deg = 0.f;

    for (int j = e0 + g; j < e1; j += 8) {
        int2 pc = epack[j];
        uint4 v = Hin[(size_t)pc.x * 32 + lane32];
        int et = pc.y;
        float w = (et == 0) ? f0 : (et == 1) ? f1 : (et == 2) ? f2 : (et == 3) ? f3 : f4;
        deg += w;
        acc[0] += w * __uint_as_float(v.x << 16);
        acc[1] += w * __uint_as_float(v.x & 0xFFFF0000u);
        acc[2] += w * __uint_as_float(v.y << 16);
        acc[3] += w * __uint_as_float(v.y & 0xFFFF0000u);
        acc[4] += w * __uint_as_float(v.z << 16);
        acc[5] += w * __uint_as_float(v.z & 0xFFFF0000u);
        acc[6] += w * __uint_as_float(v.w << 16);
        acc[7] += w * __uint_as_float(v.w & 0xFFFF0000u);
    }

    // combine the two 32-lane groups within each wave (lane l <-> l^32)
#pragma unroll
    for (int r = 0; r < 8; ++r) acc[r] += __shfl_xor(acc[r], 32);
    deg += __shfl_xor(deg, 32);

    // combine across the 4 waves via LDS (waves 1-3 write, wave 0 reduces)
    __shared__ float sacc[3][8][33];
    __shared__ float sdeg[3][33];
    int wv = t >> 6;
    bool lowhalf = (t & 63) < 32;
    if (wv > 0 && lowhalf) {
#pragma unroll
        for (int r = 0; r < 8; ++r) sacc[wv - 1][r][lane32] = acc[r];
        sdeg[wv - 1][lane32] = deg;
    }
    __syncthreads();
    if (wv == 0 && lowhalf) {
#pragma unroll
        for (int k = 0; k < 3; ++k) {
#pragma unroll
            for (int r = 0; r < 8; ++r) acc[r] += sacc[k][r][lane32];
            deg += sdeg[k][lane32];
        }
        float inv = 1.f / deg;
        uint4 o;
        o.x = (unsigned int)f2bf(acc[0] * inv) | ((unsigned int)f2bf(acc[1] * inv) << 16);
        o.y = (unsigned int)f2bf(acc[2] * inv) | ((unsigned int)f2bf(acc[3] * inv) << 16);
        o.z = (unsigned int)f2bf(acc[4] * inv) | ((unsigned int)f2bf(acc[5] * inv) << 16);
        o.w = (unsigned int)f2bf(acc[6] * inv) | ((unsigned int)f2bf(acc[7] * inv) << 16);
        Hout[(size_t)node * 32 + lane32] = o;
    }
}

// ---------------- MLP1 via MFMA on gathered interleaved rows ----------------
__global__ __launch_bounds__(256) void mlp1_mfma(const unsigned short* __restrict__ H2,
                                                 const int* __restrict__ cat,
                                                 const unsigned short* __restrict__ W1T,
                                                 const float* __restrict__ b1,
                                                 float* __restrict__ hidden, int NCAT) {
    int t = threadIdx.x;
    int wv = t >> 6, l = t & 63;
    int l15 = l & 15, lq = l >> 4;
    int i = blockIdx.x * 64 + wv * 16 + l15;
    int iclamp = i < NCAT ? i : NCAT - 1;
    int node = cat[iclamp];

    short8 bfrag[8];
    const unsigned short* xrow = H2 + (size_t)node * (CCH * HID);
#pragma unroll
    for (int kk = 0; kk < 8; ++kk)
        bfrag[kk] = *(const short8*)(xrow + kk * 32 + lq * 8);

#pragma unroll
    for (int mt = 0; mt < 8; ++mt) {
        floatx4 acc = {0.f, 0.f, 0.f, 0.f};
        const unsigned short* arow = W1T + (size_t)(mt * 16 + l15) * (CCH * HID);
#pragma unroll
        for (int kk = 0; kk < 8; ++kk) {
            short8 a = *(const short8*)(arow + kk * 32 + lq * 8);
            acc = __builtin_amdgcn_mfma_f32_16x16x32_bf16(a, bfrag[kk], acc, 0, 0, 0);
        }
        if (i < NCAT) {
            int d0 = mt * 16 + lq * 4;
            floatx4 o;
#pragma unroll
            for (int r = 0; r < 4; ++r) o[r] = fmaxf(acc[r] + b1[d0 + r], 0.f);
            *(floatx4*)(hidden + (size_t)i * HID + d0) = o;
        }
    }
}

// ---------------- MLP2 ----------------
__global__ void mlp2_kernel(const float* __restrict__ hidden, const float* __restrict__ W2,
                            const float* __restrict__ b2, float* __restrict__ out, int NCAT) {
    int idx = blockIdx.x * 256 + threadIdx.x;
    int i = idx >> 4, cls = idx & 15;
    if (i >= NCAT) return;
    const float* hrow = hidden + (size_t)i * HID;
    float acc = b2[cls];
#pragma unroll 8
    for (int j = 0; j < HID; ++j) acc += hrow[j] * W2[j * NCLS + cls];
    out[idx] = acc;
}

extern "C" void kernel_launch(void* const* d_in, const int* in_sizes, int n_in,
                              void* d_out, int out_size, void* d_ws, size_t ws_size,
                              hipStream_t stream) {
    const float* h    = (const float*)d_in[0];
    const int* src    = (const int*)d_in[1];
    const int* dst    = (const int*)d_in[2];
    const int* etype  = (const int*)d_in[3];
    const int* cat    = (const int*)d_in[4];
    const float* gt_w = (const float*)d_in[5];
    const float* Wc   = (const float*)d_in[6];
    const float* W1   = (const float*)d_in[7];
    const float* b1   = (const float*)d_in[8];
    const float* W2   = (const float*)d_in[9];
    const float* b2   = (const float*)d_in[10];
    float* out = (float*)d_out;

    const int N = in_sizes[0] / IN_DIM;   // 50000
    const int E = in_sizes[1];            // 500000
    const int NCAT = in_sizes[4];         // 10000
    const int NCHUNK = (N + 255) / 256;

    char* p = (char*)d_ws;
    auto alloc = [&](size_t bytes) {
        char* q = p;
        p += (bytes + 255) & ~(size_t)255;
        return q;
    };
    unsigned short* HA   = (unsigned short*)alloc((size_t)N * CCH * HID * 2);
    unsigned short* HB   = (unsigned short*)alloc((size_t)N * CCH * HID * 2);
    unsigned short* WcT  = (unsigned short*)alloc((size_t)CCH * HID * IN_DIM * 2);
    unsigned short* W1T  = (unsigned short*)alloc((size_t)HID * CCH * HID * 2);
    float* hidden        = (float*)alloc((size_t)NCAT * HID * 4);
    int*   counts        = (int*)alloc((size_t)N * 4);
    int*   offsets       = (int*)alloc((size_t)(N + 1) * 4);
    int*   cursor        = (int*)alloc((size_t)N * 4);
    int*   partials      = (int*)alloc((size_t)NCHUNK * 4);
    int*   chunk_off     = (int*)alloc((size_t)NCHUNK * 4);
    int2*  epack         = (int2*)alloc((size_t)E * 8);
    float* filt          = (float*)alloc((size_t)LL * CCH * RR * 4);

    hipMemsetAsync(counts, 0, (size_t)N * 4, stream);

    cvt_weights<<<(CCH * HID * IN_DIM + 255) / 256, 256, 0, stream>>>(Wc, W1, gt_w, WcT, W1T, filt);
    proj_mfma<<<(N + 63) / 64, 256, 0, stream>>>(h, WcT, HA, N);

    count_kernel<<<512, 256, 0, stream>>>(dst, counts, E);
    scanA_kernel<<<NCHUNK, 256, 0, stream>>>(counts, partials, N);
    scanB_kernel<<<1, 256, 0, stream>>>(partials, chunk_off, NCHUNK);
    scanC_kernel<<<NCHUNK, 256, 0, stream>>>(counts, chunk_off, offsets, cursor, N);
    fill_kernel<<<512, 256, 0, stream>>>(src, dst, etype, cursor, epack, E);

    agg_kernel<<<N, 256, 0, stream>>>((const uint4*)HA, (uint4*)HB,
                                      offsets, epack, filt, N);
    agg_kernel<<<N, 256, 0, stream>>>((const uint4*)HB, (uint4*)HA,
                                      offsets, epack, filt + CCH * RR, N);

    mlp1_mfma<<<(NCAT + 63) / 64, 256, 0, stream>>>(HA, cat, W1T, b1, hidden, NCAT);
    mlp2_kernel<<<(NCAT * NCLS + 255) / 256, 256, 0, stream>>>(hidden, W2, b2, out, NCAT);
}